// Round 3
// baseline (83.598 us; speedup 1.0000x reference)
//
#include <hip/hip_runtime.h>

#define NB 2
#define SS 4096
#define DD 1024
#define EE 128
#define SCALE 0.08838834764831845f   // 1/sqrt(128)

typedef __bf16 bf16x8 __attribute__((ext_vector_type(8)));
typedef __bf16 bf16x4 __attribute__((ext_vector_type(4)));
typedef float  f32x4  __attribute__((ext_vector_type(4)));

__device__ inline bf16x8 cvt8(const float* __restrict__ p) {
  float4 u0 = *(const float4*)p;
  float4 u1 = *(const float4*)(p + 4);
  bf16x8 r = { (__bf16)u0.x, (__bf16)u0.y, (__bf16)u0.z, (__bf16)u0.w,
               (__bf16)u1.x, (__bf16)u1.y, (__bf16)u1.z, (__bf16)u1.w };
  return r;
}

// ---------------------------------------------------------------------------
// K0: cast the three weight matrices to bf16, flat Wb[384][1024]
// ---------------------------------------------------------------------------
__global__ __launch_bounds__(256) void wcast_kernel(
    const float* __restrict__ qW, const float* __restrict__ kW,
    const float* __restrict__ vW, __bf16* __restrict__ Wb)
{
  const int idx = blockIdx.x * 256 + threadIdx.x;           // float4 index
  const float* src = (blockIdx.y == 0) ? qW : (blockIdx.y == 1 ? kW : vW);
  float4 v = *(const float4*)&src[(size_t)idx * 4];
  bf16x4 o = { (__bf16)v.x, (__bf16)v.y, (__bf16)v.z, (__bf16)v.w };
  *(bf16x4*)&Wb[(size_t)blockIdx.y * EE * DD + (size_t)idx * 4] = o;
}

// ---------------------------------------------------------------------------
// K1: fused QKV projection, barrier-free main loop, direct-global fragments.
// grid 512 = (256 row-groups x 2 col-halves), 256 threads (4 waves).
// Block: 32 rows x 192 cols.  Wave w: 32 rows (m=2) x 48 cols (n=3).
// Epilogue: Q -> Qbf row-major (+bias); K/V -> transpose via LDS -> KT/VT.
// ---------------------------------------------------------------------------
__global__ __launch_bounds__(256) void proj_kernel(
    const float* __restrict__ x, const __bf16* __restrict__ Wb,
    const float* __restrict__ qB, const float* __restrict__ kB,
    const float* __restrict__ vB,
    __bf16* __restrict__ Qbf, __bf16* __restrict__ KT, __bf16* __restrict__ VT)
{
  __shared__ __attribute__((aligned(16))) __bf16 Tbuf[192 * 40];

  const int tid  = threadIdx.x;
  const int w    = tid >> 6;
  const int lane = tid & 63;
  const int l15  = lane & 15, l4 = lane >> 4;
  const int rg   = blockIdx.x >> 1;
  const int h    = blockIdx.x & 1;
  const int row0 = rg * 32;

  const float*  xr0 = &x[(size_t)(row0 + l15) * DD + 8 * l4];
  const float*  xr1 = xr0 + (size_t)16 * DD;
  const __bf16* wb  = &Wb[(size_t)(h * 192 + w * 48 + l15) * DD + 8 * l4];

  f32x4 acc[2][3] = {};

  #pragma unroll 4
  for (int k0 = 0; k0 < DD; k0 += 32) {
    bf16x8 a0 = cvt8(xr0 + k0);
    bf16x8 a1 = cvt8(xr1 + k0);
    #pragma unroll
    for (int n = 0; n < 3; ++n) {
      bf16x8 bv = *(const bf16x8*)(wb + (size_t)n * 16 * DD + k0);
      acc[0][n] = __builtin_amdgcn_mfma_f32_16x16x32_bf16(a0, bv, acc[0][n], 0, 0, 0);
      acc[1][n] = __builtin_amdgcn_mfma_f32_16x16x32_bf16(a1, bv, acc[1][n], 0, 0, 0);
    }
  }

  // epilogue: D layout col=lane&15, row=(lane>>4)*4+reg (m89-verified)
  #pragma unroll
  for (int m = 0; m < 2; ++m)
    #pragma unroll
    for (int n = 0; n < 3; ++n) {
      const int colg = h * 192 + w * 48 + n * 16 + l15;
      if (colg < 128) {                      // Q
        const float bv = qB[colg];
        #pragma unroll
        for (int r = 0; r < 4; ++r) {
          int row = row0 + m * 16 + l4 * 4 + r;
          Qbf[(size_t)row * EE + colg] = (__bf16)(acc[m][n][r] + bv);
        }
      } else if (colg < 256) {               // K
        const float bv = kB[colg - 128];
        const int tc = colg - (h ? 192 : 128);   // h0: 0-63, h1: 0-63
        #pragma unroll
        for (int r = 0; r < 4; ++r)
          Tbuf[tc * 40 + m * 16 + l4 * 4 + r] = (__bf16)(acc[m][n][r] + bv);
      } else {                               // V (h1 only)
        const float bv = vB[colg - 256];
        const int tc = colg - 192;               // 64-191
        #pragma unroll
        for (int r = 0; r < 4; ++r)
          Tbuf[tc * 40 + m * 16 + l4 * 4 + r] = (__bf16)(acc[m][n][r] + bv);
      }
    }
  __syncthreads();

  const int b  = row0 >> 12;
  const int s0 = row0 & 4095;
  const int tcnt = h ? 192 : 64;
  if (tid < tcnt) {
    const __bf16* src = &Tbuf[tid * 40];
    __bf16* dst;
    if (!h)               dst = &KT[((size_t)b * EE + tid) * SS + s0];        // e 0-63
    else if (tid < 64)    dst = &KT[((size_t)b * EE + 64 + tid) * SS + s0];   // e 64-127
    else                  dst = &VT[((size_t)b * EE + (tid - 64)) * SS + s0]; // f 0-127
    f32x4 v0 = ((const f32x4*)src)[0];
    f32x4 v1 = ((const f32x4*)src)[1];
    f32x4 v2 = ((const f32x4*)src)[2];
    f32x4 v3 = ((const f32x4*)src)[3];
    ((f32x4*)dst)[0] = v0; ((f32x4*)dst)[1] = v1;
    ((f32x4*)dst)[2] = v2; ((f32x4*)dst)[3] = v3;
  }
}

// ---------------------------------------------------------------------------
// K2: partial K^T V.  grid (32 chunks, 2 batches) x 256 threads (4 waves).
// Block: 128 s-rows; wave w owns f-strip of 32, full e=128.
// ---------------------------------------------------------------------------
__global__ __launch_bounds__(256) void ktv_kernel(
    const __bf16* __restrict__ KT, const __bf16* __restrict__ VT,
    float* __restrict__ part)
{
  const int c = blockIdx.x, b = blockIdx.y;
  const int tid = threadIdx.x;
  const int w = tid >> 6, lane = tid & 63;
  const int l15 = lane & 15, l4 = lane >> 4;
  const int s0 = c * 128;
  const __bf16* Kb = KT + (size_t)b * EE * SS;
  const __bf16* Vb = VT + (size_t)b * EE * SS;

  f32x4 acc[8][2] = {};
  #pragma unroll
  for (int ks = 0; ks < 4; ++ks) {
    const int s = s0 + ks * 32 + 8 * l4;
    bf16x8 bv[2];
    #pragma unroll
    for (int j = 0; j < 2; ++j)
      bv[j] = *(const bf16x8*)&Vb[(size_t)(w * 32 + j * 16 + l15) * SS + s];
    #pragma unroll
    for (int i = 0; i < 8; ++i) {
      bf16x8 av = *(const bf16x8*)&Kb[(size_t)(i * 16 + l15) * SS + s];
      acc[i][0] = __builtin_amdgcn_mfma_f32_16x16x32_bf16(av, bv[0], acc[i][0], 0, 0, 0);
      acc[i][1] = __builtin_amdgcn_mfma_f32_16x16x32_bf16(av, bv[1], acc[i][1], 0, 0, 0);
    }
  }
  float* P = part + (size_t)(b * 32 + c) * 16384;
  #pragma unroll
  for (int i = 0; i < 8; ++i)
    #pragma unroll
    for (int j = 0; j < 2; ++j)
      #pragma unroll
      for (int r = 0; r < 4; ++r) {
        int e = i * 16 + l4 * 4 + r;
        int f = w * 32 + j * 16 + l15;
        P[e * 128 + f] = acc[i][j][r];
      }
}

// ---------------------------------------------------------------------------
// K3: reduce 32 partials -> MT[b][f][e] = scale * sum (bf16, transposed)
// ---------------------------------------------------------------------------
__global__ __launch_bounds__(256) void reduce_kernel(
    const float* __restrict__ part, __bf16* __restrict__ MT)
{
  const int b = blockIdx.y;
  const int e = blockIdx.x * 8 + (threadIdx.x >> 5);
  const int f4 = (threadIdx.x & 31) * 4;
  f32x4 s = {};
  for (int cc = 0; cc < 32; ++cc)
    s += *(const f32x4*)&part[(size_t)(b * 32 + cc) * 16384 + e * 128 + f4];
  #pragma unroll
  for (int i = 0; i < 4; ++i)
    MT[((size_t)b * EE + f4 + i) * EE + e] = (__bf16)(SCALE * s[i]);
}

// ---------------------------------------------------------------------------
// K4: O = Q * M  (MT[f][e]).  grid (64, 2) x 256 threads.
// ---------------------------------------------------------------------------
__global__ __launch_bounds__(256) void qm_kernel(
    const __bf16* __restrict__ Qbf, const __bf16* __restrict__ MT,
    float* __restrict__ out)
{
  const int b = blockIdx.y;
  const int tid = threadIdx.x;
  const int w = tid >> 6, lane = tid & 63;
  const int l15 = lane & 15, l4 = lane >> 4;
  const int row0 = blockIdx.x * 64 + w * 16;
  const __bf16* Qb = Qbf + (size_t)b * SS * EE;
  const __bf16* Mb = MT + (size_t)b * EE * EE;

  f32x4 acc[8] = {};
  #pragma unroll
  for (int ks = 0; ks < 4; ++ks) {
    const int e = ks * 32 + 8 * l4;
    bf16x8 av = *(const bf16x8*)&Qb[(size_t)(row0 + l15) * EE + e];
    #pragma unroll
    for (int j = 0; j < 8; ++j) {
      bf16x8 bv = *(const bf16x8*)&Mb[(size_t)(j * 16 + l15) * EE + e];
      acc[j] = __builtin_amdgcn_mfma_f32_16x16x32_bf16(av, bv, acc[j], 0, 0, 0);
    }
  }
  #pragma unroll
  for (int j = 0; j < 8; ++j)
    #pragma unroll
    for (int r = 0; r < 4; ++r) {
      int srow = row0 + l4 * 4 + r;
      int f = j * 16 + l15;
      out[((size_t)b * SS + srow) * EE + f] = acc[j][r];
    }
}

extern "C" void kernel_launch(void* const* d_in, const int* in_sizes, int n_in,
                              void* d_out, int out_size, void* d_ws, size_t ws_size,
                              hipStream_t stream) {
  const float* x  = (const float*)d_in[0];
  const float* qW = (const float*)d_in[1];
  const float* qB = (const float*)d_in[2];
  const float* kW = (const float*)d_in[3];
  const float* kB = (const float*)d_in[4];
  const float* vW = (const float*)d_in[5];
  const float* vB = (const float*)d_in[6];
  float* out = (float*)d_out;

  char* base = (char*)d_ws;
  __bf16* Qbf = (__bf16*)(base);                        // 2 MB
  __bf16* KT  = (__bf16*)(base + (2u << 20));           // 2 MB
  __bf16* VT  = (__bf16*)(base + (4u << 20));           // 2 MB
  float*  part= (float*) (base + (6u << 20));           // 64*64KB = 4 MB
  __bf16* MT  = (__bf16*)(base + (10u << 20));          // 64 KB
  __bf16* Wb  = (__bf16*)(base + (10u << 20) + (128u << 10)); // 768 KB

  wcast_kernel <<<dim3(128, 3), 256, 0, stream>>>(qW, kW, vW, Wb);
  proj_kernel  <<<dim3(512),    256, 0, stream>>>(x, Wb, qB, kB, vB, Qbf, KT, VT);
  ktv_kernel   <<<dim3(32, 2),  256, 0, stream>>>(KT, VT, part);
  reduce_kernel<<<dim3(16, 2),  256, 0, stream>>>(part, MT);
  qm_kernel    <<<dim3(64, 2),  256, 0, stream>>>(Qbf, MT, out);
}

// Round 4
// 53.226 us; speedup vs baseline: 1.5706x; 1.5706x over previous
//
#include <hip/hip_runtime.h>

#define NB 2
#define SS 4096
#define DD 1024
#define EE 128
#define SCALE 0.08838834764831845f   // 1/sqrt(128)

typedef __bf16 bf16x8 __attribute__((ext_vector_type(8)));
typedef float  f32x4  __attribute__((ext_vector_type(4)));

// ---------------------------------------------------------------------------
// K1: fused QKV projection GEMM (absorbs weight cast).
// grid (64 row-tiles, 3 matrices) x 512 threads (8 waves = 2 row x 4 col).
// BM=128, BN=128(=E), BK=64.  Reg-staged fp32->bf16 into XOR-swizzled LDS,
// 2-deep global prefetch, raw s_barrier (loads stay in flight across it).
// Epilogue: y==0 -> Qbf row-major; y==1/2 -> transpose to KT/VT via LDS.
// ---------------------------------------------------------------------------
__global__ __launch_bounds__(512) void proj_kernel(
    const float* __restrict__ x,
    const float* __restrict__ qW, const float* __restrict__ qB,
    const float* __restrict__ kW, const float* __restrict__ kB,
    const float* __restrict__ vW, const float* __restrict__ vB,
    __bf16* __restrict__ Qbf, __bf16* __restrict__ KT, __bf16* __restrict__ VT)
{
  __shared__ __attribute__((aligned(16))) __bf16 ldsA[2][128 * 64];
  __shared__ __attribute__((aligned(16))) __bf16 ldsB[2][128 * 64];

  const int tid  = threadIdx.x;
  const int w    = tid >> 6, lane = tid & 63;
  const int l15  = lane & 15, l4 = lane >> 4;
  const int wr   = w >> 2, wc = w & 3;          // wave tile: 64 rows x 32 cols
  const int row0 = blockIdx.x * 128;            // flat row in [0,8192)
  const int y    = blockIdx.y;                  // 0=Q 1=K 2=V
  const float* __restrict__ Wsel = (y == 0) ? qW : (y == 1 ? kW : vW);
  const float* __restrict__ bias = (y == 0) ? qB : (y == 1 ? kB : vB);

  // staging geometry: thread -> (row 0..127, 16-float segment 0..3)
  const int srow = tid >> 2;
  const int cc0  = (tid & 3) * 2;               // first 16B chunk index (of 8)
  const int rs   = srow & 7;                    // swizzle key
  const float* xA = x + (size_t)(row0 + srow) * DD + (tid & 3) * 16;
  const float* wB = Wsel + (size_t)srow * DD + (tid & 3) * 16;

  f32x4 acc[4][2] = {};
  float4 rA0[4], rB0[4], rA1[4], rB1[4];

#define ISSUE(RA, RB, t) {                                                   \
    const float* xa_ = xA + (t) * 64; const float* wb_ = wB + (t) * 64;      \
    RA[0] = *(const float4*)(xa_);      RA[1] = *(const float4*)(xa_ + 4);   \
    RA[2] = *(const float4*)(xa_ + 8);  RA[3] = *(const float4*)(xa_ + 12);  \
    RB[0] = *(const float4*)(wb_);      RB[1] = *(const float4*)(wb_ + 4);   \
    RB[2] = *(const float4*)(wb_ + 8);  RB[3] = *(const float4*)(wb_ + 12);  }

#define CVTW(R, base) {                                                      \
    bf16x8 v0_ = { (__bf16)R[0].x, (__bf16)R[0].y, (__bf16)R[0].z,           \
                   (__bf16)R[0].w, (__bf16)R[1].x, (__bf16)R[1].y,           \
                   (__bf16)R[1].z, (__bf16)R[1].w };                         \
    bf16x8 v1_ = { (__bf16)R[2].x, (__bf16)R[2].y, (__bf16)R[2].z,           \
                   (__bf16)R[2].w, (__bf16)R[3].x, (__bf16)R[3].y,           \
                   (__bf16)R[3].z, (__bf16)R[3].w };                         \
    *(bf16x8*)&base[srow * 64 + ((cc0 ^ rs) << 3)]       = v0_;              \
    *(bf16x8*)&base[srow * 64 + (((cc0 + 1) ^ rs) << 3)] = v1_;              }

#define COMPUTE(P) {                                                         \
    _Pragma("unroll") for (int ks = 0; ks < 2; ++ks) {                       \
      const int sc_ = ((ks * 4 + l4) ^ (l15 & 7)) << 3;                      \
      bf16x8 af_[4], bq_[2];                                                 \
      _Pragma("unroll") for (int m = 0; m < 4; ++m)                          \
        af_[m] = *(const bf16x8*)&ldsA[P][(wr*64 + m*16 + l15)*64 + sc_];    \
      _Pragma("unroll") for (int n = 0; n < 2; ++n)                          \
        bq_[n] = *(const bf16x8*)&ldsB[P][(wc*32 + n*16 + l15)*64 + sc_];    \
      _Pragma("unroll") for (int m = 0; m < 4; ++m)                          \
        _Pragma("unroll") for (int n = 0; n < 2; ++n)                        \
          acc[m][n] = __builtin_amdgcn_mfma_f32_16x16x32_bf16(               \
              af_[m], bq_[n], acc[m][n], 0, 0, 0);                           \
    } }

#define STEP(t, RA, RB, P) {                                                 \
    CVTW(RA, ldsA[P]); CVTW(RB, ldsB[P]);                                    \
    asm volatile("s_waitcnt lgkmcnt(0)" ::: "memory");                       \
    __builtin_amdgcn_s_barrier();                                            \
    asm volatile("" ::: "memory");                                           \
    if ((t) + 2 < 16) ISSUE(RA, RB, (t) + 2);                                \
    COMPUTE(P); }

  ISSUE(rA0, rB0, 0);
  ISSUE(rA1, rB1, 1);
  for (int tt = 0; tt < 8; ++tt) {
    STEP(2 * tt,     rA0, rB0, 0);
    STEP(2 * tt + 1, rA1, rB1, 1);
  }
  __syncthreads();

  if (y == 0) {
    #pragma unroll
    for (int m = 0; m < 4; ++m)
      #pragma unroll
      for (int n = 0; n < 2; ++n) {
        const int col = wc * 32 + n * 16 + l15;
        const float bv = bias[col];
        #pragma unroll
        for (int r = 0; r < 4; ++r) {
          const int row = row0 + wr * 64 + m * 16 + l4 * 4 + r;
          Qbf[(size_t)row * EE + col] = (__bf16)(acc[m][n][r] + bv);
        }
      }
  } else {
    __bf16* Tb = (__bf16*)ldsA;   // 32 KB: [col 0..127][128 rows, chunk-XOR]
    #pragma unroll
    for (int m = 0; m < 4; ++m)
      #pragma unroll
      for (int n = 0; n < 2; ++n) {
        const int col = wc * 32 + n * 16 + l15;
        const float bv = bias[col];
        #pragma unroll
        for (int r = 0; r < 4; ++r) {
          const int rl = wr * 64 + m * 16 + l4 * 4 + r;
          Tb[col * 128 + ((((rl >> 3) ^ (col & 7))) << 3) + (rl & 7)] =
              (__bf16)(acc[m][n][r] + bv);
        }
      }
    __syncthreads();
    const int col = tid >> 2, p2 = tid & 3, cs = col & 7;
    __bf16* dst = ((y == 1) ? KT : VT)
        + ((size_t)(row0 >> 12) * EE + col) * SS + (row0 & 4095) + p2 * 32;
    const __bf16* srcT = &Tb[col * 128];
    #pragma unroll
    for (int jj = 0; jj < 4; ++jj)
      ((bf16x8*)dst)[jj] = *(const bf16x8*)&srcT[(((p2 * 4 + jj) ^ cs) << 3)];
  }
#undef ISSUE
#undef CVTW
#undef COMPUTE
#undef STEP
}

// ---------------------------------------------------------------------------
// K2: partial K^T V.  grid (32 chunks, 2 batches) x 256 threads (4 waves).
// ---------------------------------------------------------------------------
__global__ __launch_bounds__(256) void ktv_kernel(
    const __bf16* __restrict__ KT, const __bf16* __restrict__ VT,
    float* __restrict__ part)
{
  const int c = blockIdx.x, b = blockIdx.y;
  const int tid = threadIdx.x;
  const int w = tid >> 6, lane = tid & 63;
  const int l15 = lane & 15, l4 = lane >> 4;
  const int s0 = c * 128;
  const __bf16* Kb = KT + (size_t)b * EE * SS;
  const __bf16* Vb = VT + (size_t)b * EE * SS;

  f32x4 acc[8][2] = {};
  #pragma unroll
  for (int ks = 0; ks < 4; ++ks) {
    const int s = s0 + ks * 32 + 8 * l4;
    bf16x8 bv[2];
    #pragma unroll
    for (int j = 0; j < 2; ++j)
      bv[j] = *(const bf16x8*)&Vb[(size_t)(w * 32 + j * 16 + l15) * SS + s];
    #pragma unroll
    for (int i = 0; i < 8; ++i) {
      bf16x8 av = *(const bf16x8*)&Kb[(size_t)(i * 16 + l15) * SS + s];
      acc[i][0] = __builtin_amdgcn_mfma_f32_16x16x32_bf16(av, bv[0], acc[i][0], 0, 0, 0);
      acc[i][1] = __builtin_amdgcn_mfma_f32_16x16x32_bf16(av, bv[1], acc[i][1], 0, 0, 0);
    }
  }
  float* P = part + (size_t)(b * 32 + c) * 16384;
  #pragma unroll
  for (int i = 0; i < 8; ++i)
    #pragma unroll
    for (int j = 0; j < 2; ++j)
      #pragma unroll
      for (int r = 0; r < 4; ++r) {
        int e = i * 16 + l4 * 4 + r;
        int f = w * 32 + j * 16 + l15;
        P[e * 128 + f] = acc[i][j][r];
      }
}

// ---------------------------------------------------------------------------
// K3: reduce 32 partials -> MT[b][f][e] = scale * sum (bf16, transposed)
// ---------------------------------------------------------------------------
__global__ __launch_bounds__(256) void reduce_kernel(
    const float* __restrict__ part, __bf16* __restrict__ MT)
{
  const int b = blockIdx.y;
  const int e = blockIdx.x * 8 + (threadIdx.x >> 5);
  const int f4 = (threadIdx.x & 31) * 4;
  f32x4 s = {};
  for (int cc = 0; cc < 32; ++cc)
    s += *(const f32x4*)&part[(size_t)(b * 32 + cc) * 16384 + e * 128 + f4];
  #pragma unroll
  for (int i = 0; i < 4; ++i)
    MT[((size_t)b * EE + f4 + i) * EE + e] = (__bf16)(SCALE * s[i]);
}

// ---------------------------------------------------------------------------
// K4: O = Q * M  (MT[f][e]).  grid (64, 2) x 256 threads.
// ---------------------------------------------------------------------------
__global__ __launch_bounds__(256) void qm_kernel(
    const __bf16* __restrict__ Qbf, const __bf16* __restrict__ MT,
    float* __restrict__ out)
{
  const int b = blockIdx.y;
  const int tid = threadIdx.x;
  const int w = tid >> 6, lane = tid & 63;
  const int l15 = lane & 15, l4 = lane >> 4;
  const int row0 = blockIdx.x * 64 + w * 16;
  const __bf16* Qb = Qbf + (size_t)b * SS * EE;
  const __bf16* Mb = MT + (size_t)b * EE * EE;

  f32x4 acc[8] = {};
  #pragma unroll
  for (int ks = 0; ks < 4; ++ks) {
    const int e = ks * 32 + 8 * l4;
    bf16x8 av = *(const bf16x8*)&Qb[(size_t)(row0 + l15) * EE + e];
    #pragma unroll
    for (int j = 0; j < 8; ++j) {
      bf16x8 bv = *(const bf16x8*)&Mb[(size_t)(j * 16 + l15) * EE + e];
      acc[j] = __builtin_amdgcn_mfma_f32_16x16x32_bf16(av, bv, acc[j], 0, 0, 0);
    }
  }
  #pragma unroll
  for (int j = 0; j < 8; ++j)
    #pragma unroll
    for (int r = 0; r < 4; ++r) {
      int srow = row0 + l4 * 4 + r;
      int f = j * 16 + l15;
      out[((size_t)b * SS + srow) * EE + f] = acc[j][r];
    }
}

extern "C" void kernel_launch(void* const* d_in, const int* in_sizes, int n_in,
                              void* d_out, int out_size, void* d_ws, size_t ws_size,
                              hipStream_t stream) {
  const float* x  = (const float*)d_in[0];
  const float* qW = (const float*)d_in[1];
  const float* qB = (const float*)d_in[2];
  const float* kW = (const float*)d_in[3];
  const float* kB = (const float*)d_in[4];
  const float* vW = (const float*)d_in[5];
  const float* vB = (const float*)d_in[6];
  float* out = (float*)d_out;

  char* base = (char*)d_ws;
  __bf16* Qbf = (__bf16*)(base);                        // 2 MB
  __bf16* KT  = (__bf16*)(base + (2u << 20));           // 2 MB
  __bf16* VT  = (__bf16*)(base + (4u << 20));           // 2 MB
  float*  part= (float*) (base + (6u << 20));           // 4 MB
  __bf16* MT  = (__bf16*)(base + (10u << 20));          // 64 KB

  proj_kernel  <<<dim3(64, 3), 512, 0, stream>>>(x, qW, qB, kW, kB, vW, vB,
                                                 Qbf, KT, VT);
  ktv_kernel   <<<dim3(32, 2), 256, 0, stream>>>(KT, VT, part);
  reduce_kernel<<<dim3(16, 2), 256, 0, stream>>>(part, MT);
  qm_kernel    <<<dim3(64, 2), 256, 0, stream>>>(Qbf, MT, out);
}